// Round 8
// baseline (96.748 us; speedup 1.0000x reference)
//
#include <hip/hip_runtime.h>
#include <hip/hip_fp16.h>

typedef _Float16 f16;
typedef __fp16 h16x2 __attribute__((ext_vector_type(2)));
typedef _Float16 f16x8 __attribute__((ext_vector_type(8)));
typedef _Float16 f16x4v __attribute__((ext_vector_type(4)));
typedef float f32x4 __attribute__((ext_vector_type(4)));
typedef float f32x16 __attribute__((ext_vector_type(16)));
typedef unsigned int u32;
typedef u32 u32x4 __attribute__((ext_vector_type(4)));

constexpr int DM = 1024;
constexpr int HS = 64;
constexpr int NBATCH = 4;
constexpr int T = 4096;
// softmax uses exp2; fold the 1/sqrt(64)=0.125 score scale into the exponent constant
constexpr float CEXP = 0.18033688011112042f; // 0.125 * log2(e)

#if __has_builtin(__builtin_amdgcn_exp2f)
#define EXP2(x) __builtin_amdgcn_exp2f(x)
#else
#define EXP2(x) exp2f(x)
#endif

static __device__ __forceinline__ u32 pack2_f16(float a, float b) {
  union { f16 h[2]; u32 u; } cv;
  cv.h[0] = (f16)a; cv.h[1] = (f16)b;
  return cv.u;
}

// pack 8 floats -> f16x8 via 4x v_cvt_pkrtz
static __device__ __forceinline__ f16x8 cvt8(const f32x4& a0, const f32x4& a1) {
  union { h16x2 p[4]; f16x8 v; } cv;
  cv.p[0] = __builtin_amdgcn_cvt_pkrtz(a0[0], a0[1]);
  cv.p[1] = __builtin_amdgcn_cvt_pkrtz(a0[2], a0[3]);
  cv.p[2] = __builtin_amdgcn_cvt_pkrtz(a1[0], a1[1]);
  cv.p[3] = __builtin_amdgcn_cvt_pkrtz(a1[2], a1[3]);
  return cv.v;
}

// async global->LDS, 16B per lane: LDS dest = wave-uniform base + lane*16.
static __device__ __forceinline__ void gload_lds16(const void* g, void* l) {
  __builtin_amdgcn_global_load_lds(
      (__attribute__((address_space(1))) void*)(g),
      (__attribute__((address_space(3))) void*)(l), 16, 0, 0);
}

// ---------------------------------------------------------------------------
// Prepass: W [1024][64] fp32 -> WTf, fragment-packed fp16:
// WTf[which][frag = t*4+cb][lane = g*16+q15][e] = W[k = t*32+8g+e][col = cb*16+q15]
// ---------------------------------------------------------------------------
__global__ void wtrans_kernel(const float* __restrict__ Wq, const float* __restrict__ Wk,
                              const float* __restrict__ Wv, f16* __restrict__ WTf) {
  const int which = blockIdx.y;
  const float* __restrict__ W = (which == 0) ? Wq : ((which == 1) ? Wk : Wv);
  const int o8 = blockIdx.x * 256 + threadIdx.x;   // 0 .. 8191
  const int t = o8 >> 8;
  const int cb = (o8 >> 6) & 3;
  const int g = (o8 >> 4) & 3;
  const int q15 = o8 & 15;
  const int col = cb * 16 + q15;
  f16x8 v;
#pragma unroll
  for (int e = 0; e < 8; ++e) v[e] = (f16)W[(t * 32 + 8 * g + e) * 64 + col];
  *(f16x8*)(WTf + which * 65536 + o8 * 8) = v;
}

// ---------------------------------------------------------------------------
// Projections v6: ALL-UPFRONT wave-private streaming.
// Block = 512 thr = 8 waves = one 16-row tile x 8 k-slices (128 k each).
// Per wave: issue all 8 A global_load_lds (wave-private 8KB LDS, XOR-swz
// source, 128B/row granule) + all 16 B fragment loads into fully-live
// B[16] regs (allocator cannot reuse -> forced MLP), ONE vmcnt(0), then
// 16 MFMAs straight through. Latency appears once per wave, not per iter.
// Partials overlay dead A-LDS; one barrier; 8-way reduce. 64KB LDS,
// <=128 VGPR -> 2 blocks/CU; waves fully decoupled until the reduce.
// ---------------------------------------------------------------------------
__global__ __launch_bounds__(512, 4) void proj_kernel(
    const float* __restrict__ xq, const float* __restrict__ xk, const float* __restrict__ xv,
    const f16* __restrict__ WTf, f16* __restrict__ qh, f16* __restrict__ kh,
    f16* __restrict__ vhT) {
  __shared__ __align__(16) char As[8][8192];   // wave-private: 4 chunks x 2KB

  const int which = blockIdx.y;
  const float* __restrict__ x = (which == 0) ? xq : ((which == 1) ? xk : xv);
  const int tid = threadIdx.x;
  const int lane = tid & 63, w = tid >> 6;
  const int q15 = lane & 15, g = lane >> 4;
  const int row0 = blockIdx.x * 16;
  const char* __restrict__ xbase = (const char*)x;

  // ---- A stage: 8 gloads. instr (t,j): lane -> row r = 8j+(lane>>3),
  // 128B k-run [w*128+t*32 .. +32), granule position (lane&7) holds content
  // granule (lane&7)^(r&7)  [r&7 == lane>>3]  -> inverse-swizzled source.
  const int l7 = lane & 7, l3 = lane >> 3;
  const int swz = ((l7 ^ l3) * 16);
#pragma unroll
  for (int t = 0; t < 4; ++t)
#pragma unroll
    for (int j = 0; j < 2; ++j) {
      const int r = 8 * j + l3;
      gload_lds16(xbase + (size_t)(row0 + r) * 4096 + (size_t)(w * 128 + t * 32) * 4 + swz,
                  &As[w][t * 2048 + j * 1024]);
    }

  // ---- B stage: 16 fragment loads, all live through the loop (64 VGPR).
  const char* __restrict__ wfb = (const char*)(WTf + which * 65536) + lane * 16;
  f16x8 B[16];
#pragma unroll
  for (int i = 0; i < 16; ++i)
    B[i] = *(const f16x8*)(wfb + (size_t)(w * 16 + i) * 1024);

  // ---- single one-shot drain (not in a loop), then compute straight through
  asm volatile("s_waitcnt vmcnt(0)" ::: "memory");
  __builtin_amdgcn_sched_barrier(0);

  f32x4 acc[4];
#pragma unroll
  for (int cb = 0; cb < 4; ++cb) acc[cb] = (f32x4){0.f, 0.f, 0.f, 0.f};

  const char* pa = &As[w][0] + q15 * 128;   // q15*128 = (q15>>3)*1024 + (q15&7)*128
  const int rx = (q15 & 7) * 16;
#pragma unroll
  for (int t = 0; t < 4; ++t) {
    const f32x4 a0 = *(const f32x4*)(pa + t * 2048 + (((2 * g + 0) * 16) ^ rx));
    const f32x4 a1 = *(const f32x4*)(pa + t * 2048 + (((2 * g + 1) * 16) ^ rx));
    const f16x8 af = cvt8(a0, a1);
#pragma unroll
    for (int cb = 0; cb < 4; ++cb)
      acc[cb] = __builtin_amdgcn_mfma_f32_16x16x32_f16(af, B[t * 4 + cb], acc[cb], 0, 0, 0);
  }

  // ---- partial [16 rows][64 cols] (pad 68) overlays dead A-LDS (wave-private)
  float* part = (float*)&As[w][0];
#pragma unroll
  for (int cb = 0; cb < 4; ++cb)
#pragma unroll
    for (int j = 0; j < 4; ++j)
      part[(4 * g + j) * 68 + cb * 16 + q15] = acc[cb][j];
  __syncthreads();

  // ---- 8-way reduce: thread -> (col = tid&63, row pair rp, rp+1)
  const int col = tid & 63;
  const int rp = (tid >> 6) * 2;
  float v0 = 0.f, v1 = 0.f;
#pragma unroll
  for (int w2 = 0; w2 < 8; ++w2) {
    const float* p2 = (const float*)&As[w2][0];
    v0 += p2[rp * 68 + col];
    v1 += p2[(rp + 1) * 68 + col];
  }

  if (which < 2) {
    f16* __restrict__ outp = (which == 0) ? qh : kh;
    outp[(size_t)(row0 + rp) * HS + col] = (f16)v0;
    outp[(size_t)(row0 + rp + 1) * HS + col] = (f16)v1;
  } else {
    const int b = row0 >> 12;
    const int trow = (row0 & (T - 1)) + rp;
    *(u32*)(vhT + (size_t)b * HS * T + (size_t)col * T + trow) = pack2_f16(v0, v1);
  }
}

// ---------------------------------------------------------------------------
// Causal flash attention v2: 32x32x16 MFMA, swapped form. (unchanged)
// ---------------------------------------------------------------------------
__global__ __launch_bounds__(512, 4) void attn_kernel(
    const f16* __restrict__ qh, const f16* __restrict__ kh,
    const f16* __restrict__ vhT, float* __restrict__ out) {
  __shared__ float sO[4][64][33];   // merge slots, pad 33
  __shared__ float sMm[8][32];
  __shared__ float sLs[8][32];

  const int tid = threadIdx.x;
  const int lane = tid & 63, w = tid >> 6;
  const int q31 = lane & 31, hi = lane >> 5;

  const int id = blockIdx.x;                 // 0..511
  const int b = (id & 7) >> 1;               // batch pinned to XCD pair
  const int qt = 127 - 2 * (id >> 3) - (id & 1);   // big tiles dispatched first
  const int q0 = qt * 32;

  const f16* __restrict__ kbase = kh + (size_t)b * T * HS;
  const f16* __restrict__ vbase = vhT + (size_t)b * HS * T;
  const f16* __restrict__ qp = qh + (size_t)(b * T + q0 + q31) * HS + 8 * hi;

  // Q^T as B-operand: lane holds Q[q=lane&31][d = kt*16 + 8*hi + e]
  f16x8 qb[4];
#pragma unroll
  for (int kt = 0; kt < 4; ++kt) qb[kt] = *(const f16x8*)(qp + 16 * kt);

  f32x16 o0, o1;   // O^T d-tiles [0..31], [32..63]
#pragma unroll
  for (int i = 0; i < 16; ++i) { o0[i] = 0.f; o1[i] = 0.f; }
  float m = -1e30f, lsum = 0.f;

  const int nblk = qt + 1;   // causal: KV blocks 0 .. qt
  for (int blk = w; blk < nblk; blk += 8) {
    const int kv0 = blk * 32;
    const f16* kr = kbase + (size_t)(kv0 + q31) * HS + 8 * hi;
    f16x8 ka0 = *(const f16x8*)(kr);
    f16x8 ka1 = *(const f16x8*)(kr + 16);
    f16x8 ka2 = *(const f16x8*)(kr + 32);
    f16x8 ka3 = *(const f16x8*)(kr + 48);

    f32x16 s;
#pragma unroll
    for (int i = 0; i < 16; ++i) s[i] = 0.f;
    s = __builtin_amdgcn_mfma_f32_32x32x16_f16(ka0, qb[0], s, 0, 0, 0);
    s = __builtin_amdgcn_mfma_f32_32x32x16_f16(ka1, qb[1], s, 0, 0, 0);
    s = __builtin_amdgcn_mfma_f32_32x32x16_f16(ka2, qb[2], s, 0, 0, 0);
    s = __builtin_amdgcn_mfma_f32_32x32x16_f16(ka3, qb[3], s, 0, 0, 0);
    // s[reg] = S^T[k = kv0 + (reg&3)+8*(reg>>2)+4*hi][q = q0 + q31]

    // V^T loads issued now, consumed after softmax (hide L2 latency)
    const f16* vr = vbase + (size_t)q31 * T + kv0 + 8 * hi;
    f16x8 v00 = *(const f16x8*)(vr);
    f16x8 v01 = *(const f16x8*)(vr + 16);
    f16x8 v10 = *(const f16x8*)(vr + (size_t)32 * T);
    f16x8 v11 = *(const f16x8*)(vr + (size_t)32 * T + 16);

    if (blk == qt) {   // diagonal block: mask key > q
#pragma unroll
      for (int r = 0; r < 16; ++r) {
        const int kl = (r & 3) + 8 * (r >> 2) + 4 * hi;
        if (kl > q31) s[r] = -1e30f;
      }
    }

    float pm = s[0];
#pragma unroll
    for (int r = 1; r < 16; ++r) pm = fmaxf(pm, s[r]);
    pm = fmaxf(pm, __shfl_xor(pm, 32));
    // defer-max (T13): skip O-rescale while max growth <= 32
    if (!__all(pm <= m + 32.f)) {
      const float mn = fmaxf(m, pm);
      const float r = EXP2((m - mn) * CEXP);
      lsum *= r;
#pragma unroll
      for (int i = 0; i < 16; ++i) { o0[i] *= r; o1[i] *= r; }
      m = mn;
    }

    float p[16];
    float ps = 0.f;
#pragma unroll
    for (int r = 0; r < 16; ++r) { p[r] = EXP2((s[r] - m) * CEXP); ps += p[r]; }
    ps += __shfl_xor(ps, 32);
    lsum += ps;

    u32 c[8], xg[8];
#pragma unroll
    for (int i = 0; i < 8; ++i) c[i] = pack2_f16(p[2 * i], p[2 * i + 1]);
#pragma unroll
    for (int i = 0; i < 8; ++i) xg[i] = (u32)__shfl_xor((int)c[i], 32);
    union { u32x4 u; f16x8 f; } f1, f2;
    f1.u = (u32x4){ hi ? xg[2] : c[0], hi ? xg[3] : c[1], hi ? c[2] : xg[0], hi ? c[3] : xg[1] };
    f2.u = (u32x4){ hi ? xg[6] : c[4], hi ? xg[7] : c[5], hi ? c[6] : xg[4], hi ? c[7] : xg[5] };

    o0 = __builtin_amdgcn_mfma_f32_32x32x16_f16(v00, f1.f, o0, 0, 0, 0);
    o0 = __builtin_amdgcn_mfma_f32_32x32x16_f16(v01, f2.f, o0, 0, 0, 0);
    o1 = __builtin_amdgcn_mfma_f32_32x32x16_f16(v10, f1.f, o1, 0, 0, 0);
    o1 = __builtin_amdgcn_mfma_f32_32x32x16_f16(v11, f2.f, o1, 0, 0, 0);
  }

  // ---- cross-wave merge under common max M ----
  if (lane < 32) sMm[w][q31] = m;
  __syncthreads();
  float M = sMm[0][q31];
#pragma unroll
  for (int w2 = 1; w2 < 8; ++w2) M = fmaxf(M, sMm[w2][q31]);
  const float sc = EXP2((m - M) * CEXP);   // idle waves: exp2(-huge)=0
  if (lane < 32) sLs[w][q31] = lsum * sc;
#pragma unroll
  for (int i = 0; i < 16; ++i) { o0[i] *= sc; o1[i] *= sc; }

  if (w >= 4) {
#pragma unroll
    for (int r = 0; r < 16; ++r) {
      const int d = (r & 3) + 8 * (r >> 2) + 4 * hi;
      sO[w - 4][d][q31] = o0[r];
      sO[w - 4][d + 32][q31] = o1[r];
    }
  }
  __syncthreads();
  if (w < 4) {
#pragma unroll
    for (int r = 0; r < 16; ++r) {
      const int d = (r & 3) + 8 * (r >> 2) + 4 * hi;
      sO[w][d][q31] += o0[r];
      sO[w][d + 32][q31] += o1[r];
    }
  }
  __syncthreads();

  // ---- normalize + coalesced float4 store
  const int q = tid >> 4;
  const int d0 = (tid & 15) * 4;
  float L = 0.f;
#pragma unroll
  for (int w2 = 0; w2 < 8; ++w2) L += sLs[w2][q];
  const float invL = 1.f / L;
  float4 rv;
  rv.x = (sO[0][d0 + 0][q] + sO[1][d0 + 0][q] + sO[2][d0 + 0][q] + sO[3][d0 + 0][q]) * invL;
  rv.y = (sO[0][d0 + 1][q] + sO[1][d0 + 1][q] + sO[2][d0 + 1][q] + sO[3][d0 + 1][q]) * invL;
  rv.z = (sO[0][d0 + 2][q] + sO[1][d0 + 2][q] + sO[2][d0 + 2][q] + sO[3][d0 + 2][q]) * invL;
  rv.w = (sO[0][d0 + 3][q] + sO[1][d0 + 3][q] + sO[2][d0 + 3][q] + sO[3][d0 + 3][q]) * invL;
  *(float4*)(out + (size_t)(b * T + q0 + q) * HS + d0) = rv;
}

// ---------------------------------------------------------------------------
extern "C" void kernel_launch(void* const* d_in, const int* in_sizes, int n_in,
                              void* d_out, int out_size, void* d_ws, size_t ws_size,
                              hipStream_t stream) {
  const float* q  = (const float*)d_in[0];
  const float* k  = (const float*)d_in[1];
  const float* v  = (const float*)d_in[2];
  const float* Wq = (const float*)d_in[3];
  const float* Wk = (const float*)d_in[4];
  const float* Wv = (const float*)d_in[5];
  // d_in[6] attn_mask: known lower-triangular causal; handled analytically.
  float* out = (float*)d_out;

  f16* qh  = (f16*)d_ws;                       // [B*T][64]
  f16* kh  = qh  + (size_t)NBATCH * T * HS;    // [B*T][64]
  f16* vhT = kh  + (size_t)NBATCH * T * HS;    // [B][64][T]
  f16* WTf = vhT + (size_t)NBATCH * T * HS;    // [3][65536] fragment-packed

  wtrans_kernel<<<dim3(32, 3), 256, 0, stream>>>(Wq, Wk, Wv, WTf);
  proj_kernel<<<dim3(NBATCH * T / 16, 3), 512, 0, stream>>>(q, k, v, WTf, qh, kh, vhT);
  attn_kernel<<<dim3(T / 32 * NBATCH), 512, 0, stream>>>(qh, kh, vhT, out);
}

// Round 9
// 91.187 us; speedup vs baseline: 1.0610x; 1.0610x over previous
//
#include <hip/hip_runtime.h>
#include <hip/hip_fp16.h>

typedef _Float16 f16;
typedef __fp16 h16x2 __attribute__((ext_vector_type(2)));
typedef _Float16 f16x8 __attribute__((ext_vector_type(8)));
typedef _Float16 f16x4v __attribute__((ext_vector_type(4)));
typedef float f32x4 __attribute__((ext_vector_type(4)));
typedef float f32x16 __attribute__((ext_vector_type(16)));
typedef unsigned int u32;
typedef u32 u32x4 __attribute__((ext_vector_type(4)));

constexpr int DM = 1024;
constexpr int HS = 64;
constexpr int NBATCH = 4;
constexpr int T = 4096;
constexpr float CEXP = 0.18033688011112042f; // 0.125 * log2(e)

#if __has_builtin(__builtin_amdgcn_exp2f)
#define EXP2(x) __builtin_amdgcn_exp2f(x)
#else
#define EXP2(x) exp2f(x)
#endif

static __device__ __forceinline__ u32 pack2_f16(float a, float b) {
  union { f16 h[2]; u32 u; } cv;
  cv.h[0] = (f16)a; cv.h[1] = (f16)b;
  return cv.u;
}

static __device__ __forceinline__ f16x8 cvt8(const f32x4& a0, const f32x4& a1) {
  union { h16x2 p[4]; f16x8 v; } cv;
  cv.p[0] = __builtin_amdgcn_cvt_pkrtz(a0[0], a0[1]);
  cv.p[1] = __builtin_amdgcn_cvt_pkrtz(a0[2], a0[3]);
  cv.p[2] = __builtin_amdgcn_cvt_pkrtz(a1[0], a1[1]);
  cv.p[3] = __builtin_amdgcn_cvt_pkrtz(a1[2], a1[3]);
  return cv.v;
}

// async global->LDS, 16B/lane; dest is wave-uniform base (HW adds lane*16)
static __device__ __forceinline__ void gload_lds16(const void* g, void* l) {
  __builtin_amdgcn_global_load_lds(
      (__attribute__((address_space(1))) void*)(g),
      (__attribute__((address_space(3))) void*)(l), 16, 0, 0);
}

// ---------------------------------------------------------------------------
// Prepass: W [1024][64] fp32 -> WTf fragment-packed fp16:
// WTf[which][frag = t*4+cb][lane = g*16+q15][e] = W[k = t*32+8g+e][col = cb*16+q15]
// ---------------------------------------------------------------------------
__global__ void wtrans_kernel(const float* __restrict__ Wq, const float* __restrict__ Wk,
                              const float* __restrict__ Wv, f16* __restrict__ WTf) {
  const int which = blockIdx.y;
  const float* __restrict__ W = (which == 0) ? Wq : ((which == 1) ? Wk : Wv);
  const int o8 = blockIdx.x * 256 + threadIdx.x;   // 0 .. 8191
  const int t = o8 >> 8;
  const int cb = (o8 >> 6) & 3;
  const int g = (o8 >> 4) & 3;
  const int q15 = o8 & 15;
  const int col = cb * 16 + q15;
  f16x8 v;
#pragma unroll
  for (int e = 0; e < 8; ++e) v[e] = (f16)W[(t * 32 + 8 * g + e) * 64 + col];
  *(f16x8*)(WTf + which * 65536 + o8 * 8) = v;
}

// ---------------------------------------------------------------------------
// Projections v7: B fully LDS-resident + asm-pipelined A stream.
// Block = 256 thr = 4 waves x 16 rows (64 rows), FULL K per wave (no reduce).
// (1) 32 gload_lds stage ALL of WTf[which] (128KB) into LDS once; barrier.
//     Kills the 384MB B-redundancy of r7/r8 (-> 98MB, L2-only).
// (2) A: inline-asm global_load_dwordx4 into statically-indexed f32x4 ld[16][4]
//     (asm dsts -> allocator MUST keep live; asm volatile order is fixed),
//     depth-4 sets, counted s_waitcnt vmcnt(12) per step (AITER pattern),
//     sched_barrier(0) fences (rule: MFMA hoisting past asm waits).
// 16 outstanding 1KB loads/wave; zero barriers after B-stage.
// ---------------------------------------------------------------------------
__global__ __launch_bounds__(256) void proj_kernel(
    const float* __restrict__ xq, const float* __restrict__ xk, const float* __restrict__ xv,
    const f16* __restrict__ WTf, f16* __restrict__ qh, f16* __restrict__ kh,
    f16* __restrict__ vhT) {
  __shared__ __align__(16) char Bs[131072];   // all 64 B-fragment groups

  const int which = blockIdx.y;
  const float* __restrict__ x = (which == 0) ? xq : ((which == 1) ? xk : xv);
  const int tid = threadIdx.x;
  const int lane = tid & 63, w = tid >> 6;
  const int q15 = lane & 15, g = lane >> 4;
  const int row0 = blockIdx.x * 64 + w * 16;

  // ---- stage B: WTf[which] (128KB) -> LDS, linear both sides
  const char* __restrict__ wsrc = (const char*)(WTf + (size_t)which * 65536);
#pragma unroll
  for (int j = 0; j < 32; ++j)
    gload_lds16(wsrc + j * 4096 + w * 1024 + (lane & 63) * 16,
                &Bs[j * 4096 + w * 1024]);
  __builtin_amdgcn_sched_barrier(0);   // keep B-stage issued before A-issue

  // ---- A: issue prologue sets 0..3 (asm, ordered)
  const size_t aaddr =
      (size_t)((const char*)x + (size_t)(row0 + q15) * 4096 + 32 * g);
  f32x4 ld[16][4];
#define AISSUE(s)                                                                       \
  {                                                                                     \
    const size_t ab = aaddr + (size_t)((s) * 256);                                      \
    asm volatile("global_load_dwordx4 %0, %1, off"            : "=v"(ld[s][0]) : "v"(ab)); \
    asm volatile("global_load_dwordx4 %0, %1, off offset:16"  : "=v"(ld[s][1]) : "v"(ab)); \
    asm volatile("global_load_dwordx4 %0, %1, off offset:128" : "=v"(ld[s][2]) : "v"(ab)); \
    asm volatile("global_load_dwordx4 %0, %1, off offset:144" : "=v"(ld[s][3]) : "v"(ab)); \
  }
  AISSUE(0) AISSUE(1) AISSUE(2) AISSUE(3)

  // B-stage (my 32 oldest) done; my 16 A-loads stay in flight
  asm volatile("s_waitcnt vmcnt(16)" ::: "memory");
  __builtin_amdgcn_sched_barrier(0);
  __builtin_amdgcn_s_barrier();
  __builtin_amdgcn_sched_barrier(0);

  f32x4 acc[4];
#pragma unroll
  for (int cb = 0; cb < 4; ++cb) acc[cb] = (f32x4){0.f, 0.f, 0.f, 0.f};

#pragma unroll
  for (int s = 0; s < 16; ++s) {
    if (s < 13)      asm volatile("s_waitcnt vmcnt(12)" ::: "memory");
    else if (s == 13) asm volatile("s_waitcnt vmcnt(8)" ::: "memory");
    else if (s == 14) asm volatile("s_waitcnt vmcnt(4)" ::: "memory");
    else              asm volatile("s_waitcnt vmcnt(0)" ::: "memory");
    __builtin_amdgcn_sched_barrier(0);
    if (s + 4 < 16) AISSUE(s + 4)

    const f16x8 af0 = cvt8(ld[s][0], ld[s][1]);   // kstep 2s
    const f16x8 af1 = cvt8(ld[s][2], ld[s][3]);   // kstep 2s+1
    const char* bb = &Bs[0] + s * 8192 + lane * 16;
#pragma unroll
    for (int cb = 0; cb < 4; ++cb) {
      const f16x8 b0 = *(const f16x8*)(bb + cb * 1024);
      acc[cb] = __builtin_amdgcn_mfma_f32_16x16x32_f16(af0, b0, acc[cb], 0, 0, 0);
    }
#pragma unroll
    for (int cb = 0; cb < 4; ++cb) {
      const f16x8 b1 = *(const f16x8*)(bb + 4096 + cb * 1024);
      acc[cb] = __builtin_amdgcn_mfma_f32_16x16x32_f16(af1, b1, acc[cb], 0, 0, 0);
    }
  }
#undef AISSUE

  // ---- epilogue (r2-verified layout: row = 4g+j, col = cb*16+q15)
  if (which < 2) {
    f16* __restrict__ outp = (which == 0) ? qh : kh;
#pragma unroll
    for (int cb = 0; cb < 4; ++cb)
#pragma unroll
      for (int j = 0; j < 4; ++j)
        outp[(size_t)(row0 + 4 * g + j) * HS + cb * 16 + q15] = (f16)acc[cb][j];
  } else {
    const int b = row0 >> 12;
    const int t0 = (row0 & (T - 1)) + 4 * g;
#pragma unroll
    for (int cb = 0; cb < 4; ++cb) {
      f16x4v pv;
#pragma unroll
      for (int j = 0; j < 4; ++j) pv[j] = (f16)acc[cb][j];
      *(f16x4v*)(vhT + (size_t)b * HS * T + (size_t)(cb * 16 + q15) * T + t0) = pv;
    }
  }
}

// ---------------------------------------------------------------------------
// Causal flash attention: 32x32x16 MFMA, swapped form. (unchanged)
// ---------------------------------------------------------------------------
__global__ __launch_bounds__(512, 4) void attn_kernel(
    const f16* __restrict__ qh, const f16* __restrict__ kh,
    const f16* __restrict__ vhT, float* __restrict__ out) {
  __shared__ float sO[4][64][33];
  __shared__ float sMm[8][32];
  __shared__ float sLs[8][32];

  const int tid = threadIdx.x;
  const int lane = tid & 63, w = tid >> 6;
  const int q31 = lane & 31, hi = lane >> 5;

  const int id = blockIdx.x;
  const int b = (id & 7) >> 1;
  const int qt = 127 - 2 * (id >> 3) - (id & 1);
  const int q0 = qt * 32;

  const f16* __restrict__ kbase = kh + (size_t)b * T * HS;
  const f16* __restrict__ vbase = vhT + (size_t)b * HS * T;
  const f16* __restrict__ qp = qh + (size_t)(b * T + q0 + q31) * HS + 8 * hi;

  f16x8 qb[4];
#pragma unroll
  for (int kt = 0; kt < 4; ++kt) qb[kt] = *(const f16x8*)(qp + 16 * kt);

  f32x16 o0, o1;
#pragma unroll
  for (int i = 0; i < 16; ++i) { o0[i] = 0.f; o1[i] = 0.f; }
  float m = -1e30f, lsum = 0.f;

  const int nblk = qt + 1;
  for (int blk = w; blk < nblk; blk += 8) {
    const int kv0 = blk * 32;
    const f16* kr = kbase + (size_t)(kv0 + q31) * HS + 8 * hi;
    f16x8 ka0 = *(const f16x8*)(kr);
    f16x8 ka1 = *(const f16x8*)(kr + 16);
    f16x8 ka2 = *(const f16x8*)(kr + 32);
    f16x8 ka3 = *(const f16x8*)(kr + 48);

    f32x16 s;
#pragma unroll
    for (int i = 0; i < 16; ++i) s[i] = 0.f;
    s = __builtin_amdgcn_mfma_f32_32x32x16_f16(ka0, qb[0], s, 0, 0, 0);
    s = __builtin_amdgcn_mfma_f32_32x32x16_f16(ka1, qb[1], s, 0, 0, 0);
    s = __builtin_amdgcn_mfma_f32_32x32x16_f16(ka2, qb[2], s, 0, 0, 0);
    s = __builtin_amdgcn_mfma_f32_32x32x16_f16(ka3, qb[3], s, 0, 0, 0);

    const f16* vr = vbase + (size_t)q31 * T + kv0 + 8 * hi;
    f16x8 v00 = *(const f16x8*)(vr);
    f16x8 v01 = *(const f16x8*)(vr + 16);
    f16x8 v10 = *(const f16x8*)(vr + (size_t)32 * T);
    f16x8 v11 = *(const f16x8*)(vr + (size_t)32 * T + 16);

    if (blk == qt) {
#pragma unroll
      for (int r = 0; r < 16; ++r) {
        const int kl = (r & 3) + 8 * (r >> 2) + 4 * hi;
        if (kl > q31) s[r] = -1e30f;
      }
    }

    float pm = s[0];
#pragma unroll
    for (int r = 1; r < 16; ++r) pm = fmaxf(pm, s[r]);
    pm = fmaxf(pm, __shfl_xor(pm, 32));
    if (!__all(pm <= m + 32.f)) {
      const float mn = fmaxf(m, pm);
      const float r = EXP2((m - mn) * CEXP);
      lsum *= r;
#pragma unroll
      for (int i = 0; i < 16; ++i) { o0[i] *= r; o1[i] *= r; }
      m = mn;
    }

    float p[16];
    float ps = 0.f;
#pragma unroll
    for (int r = 0; r < 16; ++r) { p[r] = EXP2((s[r] - m) * CEXP); ps += p[r]; }
    ps += __shfl_xor(ps, 32);
    lsum += ps;

    u32 c[8], xg[8];
#pragma unroll
    for (int i = 0; i < 8; ++i) c[i] = pack2_f16(p[2 * i], p[2 * i + 1]);
#pragma unroll
    for (int i = 0; i < 8; ++i) xg[i] = (u32)__shfl_xor((int)c[i], 32);
    union { u32x4 u; f16x8 f; } f1, f2;
    f1.u = (u32x4){ hi ? xg[2] : c[0], hi ? xg[3] : c[1], hi ? c[2] : xg[0], hi ? c[3] : xg[1] };
    f2.u = (u32x4){ hi ? xg[6] : c[4], hi ? xg[7] : c[5], hi ? c[6] : xg[4], hi ? c[7] : xg[5] };

    o0 = __builtin_amdgcn_mfma_f32_32x32x16_f16(v00, f1.f, o0, 0, 0, 0);
    o0 = __builtin_amdgcn_mfma_f32_32x32x16_f16(v01, f2.f, o0, 0, 0, 0);
    o1 = __builtin_amdgcn_mfma_f32_32x32x16_f16(v10, f1.f, o1, 0, 0, 0);
    o1 = __builtin_amdgcn_mfma_f32_32x32x16_f16(v11, f2.f, o1, 0, 0, 0);
  }

  if (lane < 32) sMm[w][q31] = m;
  __syncthreads();
  float M = sMm[0][q31];
#pragma unroll
  for (int w2 = 1; w2 < 8; ++w2) M = fmaxf(M, sMm[w2][q31]);
  const float sc = EXP2((m - M) * CEXP);
  if (lane < 32) sLs[w][q31] = lsum * sc;
#pragma unroll
  for (int i = 0; i < 16; ++i) { o0[i] *= sc; o1[i] *= sc; }

  if (w >= 4) {
#pragma unroll
    for (int r = 0; r < 16; ++r) {
      const int d = (r & 3) + 8 * (r >> 2) + 4 * hi;
      sO[w - 4][d][q31] = o0[r];
      sO[w - 4][d + 32][q31] = o1[r];
    }
  }
  __syncthreads();
  if (w < 4) {
#pragma unroll
    for (int r = 0; r < 16; ++r) {
      const int d = (r & 3) + 8 * (r >> 2) + 4 * hi;
      sO[w][d][q31] += o0[r];
      sO[w][d + 32][q31] += o1[r];
    }
  }
  __syncthreads();

  const int q = tid >> 4;
  const int d0 = (tid & 15) * 4;
  float L = 0.f;
#pragma unroll
  for (int w2 = 0; w2 < 8; ++w2) L += sLs[w2][q];
  const float invL = 1.f / L;
  float4 rv;
  rv.x = (sO[0][d0 + 0][q] + sO[1][d0 + 0][q] + sO[2][d0 + 0][q] + sO[3][d0 + 0][q]) * invL;
  rv.y = (sO[0][d0 + 1][q] + sO[1][d0 + 1][q] + sO[2][d0 + 1][q] + sO[3][d0 + 1][q]) * invL;
  rv.z = (sO[0][d0 + 2][q] + sO[1][d0 + 2][q] + sO[2][d0 + 2][q] + sO[3][d0 + 2][q]) * invL;
  rv.w = (sO[0][d0 + 3][q] + sO[1][d0 + 3][q] + sO[2][d0 + 3][q] + sO[3][d0 + 3][q]) * invL;
  *(float4*)(out + (size_t)(b * T + q0 + q) * HS + d0) = rv;
}

// ---------------------------------------------------------------------------
extern "C" void kernel_launch(void* const* d_in, const int* in_sizes, int n_in,
                              void* d_out, int out_size, void* d_ws, size_t ws_size,
                              hipStream_t stream) {
  const float* q  = (const float*)d_in[0];
  const float* k  = (const float*)d_in[1];
  const float* v  = (const float*)d_in[2];
  const float* Wq = (const float*)d_in[3];
  const float* Wk = (const float*)d_in[4];
  const float* Wv = (const float*)d_in[5];
  float* out = (float*)d_out;

  f16* qh  = (f16*)d_ws;                       // [B*T][64]
  f16* kh  = qh  + (size_t)NBATCH * T * HS;    // [B*T][64]
  f16* vhT = kh  + (size_t)NBATCH * T * HS;    // [B][64][T]
  f16* WTf = vhT + (size_t)NBATCH * T * HS;    // [3][65536] fragment-packed

  wtrans_kernel<<<dim3(32, 3), 256, 0, stream>>>(Wq, Wk, Wv, WTf);
  proj_kernel<<<dim3(256, 3), 256, 0, stream>>>(q, k, v, WTf, qh, kh, vhT);
  attn_kernel<<<dim3(T / 32 * NBATCH), 512, 0, stream>>>(qh, kh, vhT, out);
}

// Round 10
// 89.304 us; speedup vs baseline: 1.0834x; 1.0211x over previous
//
#include <hip/hip_runtime.h>
#include <hip/hip_fp16.h>

typedef _Float16 f16;
typedef __fp16 h16x2 __attribute__((ext_vector_type(2)));
typedef _Float16 f16x8 __attribute__((ext_vector_type(8)));
typedef _Float16 f16x4v __attribute__((ext_vector_type(4)));
typedef float f32x4 __attribute__((ext_vector_type(4)));
typedef float f32x16 __attribute__((ext_vector_type(16)));
typedef unsigned int u32;
typedef u32 u32x4 __attribute__((ext_vector_type(4)));

constexpr int DM = 1024;
constexpr int HS = 64;
constexpr int NBATCH = 4;
constexpr int T = 4096;
constexpr float CEXP = 0.18033688011112042f; // 0.125 * log2(e)

#if __has_builtin(__builtin_amdgcn_exp2f)
#define EXP2(x) __builtin_amdgcn_exp2f(x)
#else
#define EXP2(x) exp2f(x)
#endif

static __device__ __forceinline__ u32 pack2_f16(float a, float b) {
  union { f16 h[2]; u32 u; } cv;
  cv.h[0] = (f16)a; cv.h[1] = (f16)b;
  return cv.u;
}

static __device__ __forceinline__ f16x8 cvt8(const f32x4& a0, const f32x4& a1) {
  union { h16x2 p[4]; f16x8 v; } cv;
  cv.p[0] = __builtin_amdgcn_cvt_pkrtz(a0[0], a0[1]);
  cv.p[1] = __builtin_amdgcn_cvt_pkrtz(a0[2], a0[3]);
  cv.p[2] = __builtin_amdgcn_cvt_pkrtz(a1[0], a1[1]);
  cv.p[3] = __builtin_amdgcn_cvt_pkrtz(a1[2], a1[3]);
  return cv.v;
}

static __device__ __forceinline__ void gload_lds16(const void* g, void* l) {
  __builtin_amdgcn_global_load_lds(
      (__attribute__((address_space(1))) void*)(g),
      (__attribute__((address_space(3))) void*)(l), 16, 0, 0);
}

// ---------------------------------------------------------------------------
// Prepass: W [1024][64] fp32 -> WTf fragment-packed fp16:
// WTf[which][frag = t*4+cb][lane = g*16+q15][e] = W[k = t*32+8g+e][col = cb*16+q15]
// ---------------------------------------------------------------------------
__global__ void wtrans_kernel(const float* __restrict__ Wq, const float* __restrict__ Wk,
                              const float* __restrict__ Wv, f16* __restrict__ WTf) {
  const int which = blockIdx.y;
  const float* __restrict__ W = (which == 0) ? Wq : ((which == 1) ? Wk : Wv);
  const int o8 = blockIdx.x * 256 + threadIdx.x;   // 0 .. 8191
  const int t = o8 >> 8;
  const int cb = (o8 >> 6) & 3;
  const int g = (o8 >> 4) & 3;
  const int q15 = o8 & 15;
  const int col = cb * 16 + q15;
  f16x8 v;
#pragma unroll
  for (int e = 0; e < 8; ++e) v[e] = (f16)W[(t * 32 + 8 * g + e) * 64 + col];
  *(f16x8*)(WTf + which * 65536 + o8 * 8) = v;
}

// ---------------------------------------------------------------------------
// Projections v8: PERSISTENT blocks, one continuous 64-step asm pipeline.
// Grid = 64 x 3 = 192 blocks (all co-resident, ONE round). Block = 4 waves x
// 16 rows x 4 tiles = 256 rows, full K per wave (no reduce). B (128KB WTf)
// LDS-resident, staged once. A: inline-asm global_load_dwordx4, slot-rotated
// ld[8][4], depth-4 sets, counted vmcnt(12) per step (tail 12/8/4/0), one
// cross-tile pipeline with NO mid-stream stores: acc[4][4] (64 VGPR) holds
// all 4 tiles, stores happen once after the final drain. LDS caps us at
// 1 wave/SIMD so VGPR is free -> launch_bounds(256,1).
// ---------------------------------------------------------------------------
__global__ __launch_bounds__(256, 1) void proj_kernel(
    const float* __restrict__ xq, const float* __restrict__ xk, const float* __restrict__ xv,
    const f16* __restrict__ WTf, f16* __restrict__ qh, f16* __restrict__ kh,
    f16* __restrict__ vhT) {
  __shared__ __align__(16) char Bs[131072];

  const int which = blockIdx.y;
  const float* __restrict__ x = (which == 0) ? xq : ((which == 1) ? xk : xv);
  const int tid = threadIdx.x;
  const int lane = tid & 63, w = tid >> 6;
  const int q15 = lane & 15, g = lane >> 4;

  // ---- stage B once: WTf[which] (128KB) -> LDS, linear both sides
  const char* __restrict__ wsrc = (const char*)(WTf + (size_t)which * 65536);
#pragma unroll
  for (int j = 0; j < 32; ++j)
    gload_lds16(wsrc + j * 4096 + w * 1024 + lane * 16, &Bs[j * 4096 + w * 1024]);
  __builtin_amdgcn_sched_barrier(0);

  // per-lane A base: block rows [bx*256, bx*256+256); tile t adds t*64 rows
  const size_t abase = (size_t)((const char*)x +
      ((size_t)blockIdx.x * 256 + w * 16 + q15) * 4096 + 32 * g);

#define AISSUE(slot, G2)                                                        \
  {                                                                             \
    const size_t ab = abase + (size_t)((G2) >> 4) * 262144 /*64 rows*/          \
                    + (size_t)((G2) & 15) * 256;                                \
    asm volatile("global_load_dwordx4 %0, %1, off"            : "=v"(ld[slot][0]) : "v"(ab)); \
    asm volatile("global_load_dwordx4 %0, %1, off offset:16"  : "=v"(ld[slot][1]) : "v"(ab)); \
    asm volatile("global_load_dwordx4 %0, %1, off offset:128" : "=v"(ld[slot][2]) : "v"(ab)); \
    asm volatile("global_load_dwordx4 %0, %1, off offset:144" : "=v"(ld[slot][3]) : "v"(ab)); \
  }

  f32x4 ld[8][4];
  AISSUE(0, 0) AISSUE(1, 1) AISSUE(2, 2) AISSUE(3, 3)

  // drain the 32 B-stage gloads (oldest); keep 16 A-loads in flight
  asm volatile("s_waitcnt vmcnt(16)" ::: "memory");
  __builtin_amdgcn_sched_barrier(0);
  __builtin_amdgcn_s_barrier();
  __builtin_amdgcn_sched_barrier(0);

  f32x4 acc[4][4];   // [tile][cb]
#pragma unroll
  for (int t = 0; t < 4; ++t)
#pragma unroll
    for (int cb = 0; cb < 4; ++cb) acc[t][cb] = (f32x4){0.f, 0.f, 0.f, 0.f};

#pragma unroll
  for (int G = 0; G < 64; ++G) {
    const int t = G >> 4, s = G & 15, slot = G & 7;
    if (G < 61)      asm volatile("s_waitcnt vmcnt(12)" ::: "memory");
    else if (G == 61) asm volatile("s_waitcnt vmcnt(8)" ::: "memory");
    else if (G == 62) asm volatile("s_waitcnt vmcnt(4)" ::: "memory");
    else              asm volatile("s_waitcnt vmcnt(0)" ::: "memory");
    __builtin_amdgcn_sched_barrier(0);
    if (G + 4 < 64) AISSUE((G + 4) & 7, G + 4)

    const f16x8 af0 = cvt8(ld[slot][0], ld[slot][1]);   // kstep 2s
    const f16x8 af1 = cvt8(ld[slot][2], ld[slot][3]);   // kstep 2s+1
    const char* bb = &Bs[0] + s * 8192 + lane * 16;
#pragma unroll
    for (int cb = 0; cb < 4; ++cb) {
      const f16x8 b0 = *(const f16x8*)(bb + cb * 1024);
      acc[t][cb] = __builtin_amdgcn_mfma_f32_16x16x32_f16(af0, b0, acc[t][cb], 0, 0, 0);
    }
#pragma unroll
    for (int cb = 0; cb < 4; ++cb) {
      const f16x8 b1 = *(const f16x8*)(bb + 4096 + cb * 1024);
      acc[t][cb] = __builtin_amdgcn_mfma_f32_16x16x32_f16(af1, b1, acc[t][cb], 0, 0, 0);
    }
  }
#undef AISSUE

  // ---- single store phase (queue never mixed with the pipeline)
#pragma unroll
  for (int t = 0; t < 4; ++t) {
    const int row0 = blockIdx.x * 256 + t * 64 + w * 16;
    if (which < 2) {
      f16* __restrict__ outp = (which == 0) ? qh : kh;
#pragma unroll
      for (int cb = 0; cb < 4; ++cb)
#pragma unroll
        for (int j = 0; j < 4; ++j)
          outp[(size_t)(row0 + 4 * g + j) * HS + cb * 16 + q15] = (f16)acc[t][cb][j];
    } else {
      const int b = row0 >> 12;
      const int t0 = (row0 & (T - 1)) + 4 * g;
#pragma unroll
      for (int cb = 0; cb < 4; ++cb) {
        f16x4v pv;
#pragma unroll
        for (int j = 0; j < 4; ++j) pv[j] = (f16)acc[t][cb][j];
        *(f16x4v*)(vhT + (size_t)b * HS * T + (size_t)(cb * 16 + q15) * T + t0) = pv;
      }
    }
  }
}

// ---------------------------------------------------------------------------
// Causal flash attention: 32x32x16 MFMA, swapped form. (unchanged)
// ---------------------------------------------------------------------------
__global__ __launch_bounds__(512, 4) void attn_kernel(
    const f16* __restrict__ qh, const f16* __restrict__ kh,
    const f16* __restrict__ vhT, float* __restrict__ out) {
  __shared__ float sO[4][64][33];
  __shared__ float sMm[8][32];
  __shared__ float sLs[8][32];

  const int tid = threadIdx.x;
  const int lane = tid & 63, w = tid >> 6;
  const int q31 = lane & 31, hi = lane >> 5;

  const int id = blockIdx.x;
  const int b = (id & 7) >> 1;
  const int qt = 127 - 2 * (id >> 3) - (id & 1);
  const int q0 = qt * 32;

  const f16* __restrict__ kbase = kh + (size_t)b * T * HS;
  const f16* __restrict__ vbase = vhT + (size_t)b * HS * T;
  const f16* __restrict__ qp = qh + (size_t)(b * T + q0 + q31) * HS + 8 * hi;

  f16x8 qb[4];
#pragma unroll
  for (int kt = 0; kt < 4; ++kt) qb[kt] = *(const f16x8*)(qp + 16 * kt);

  f32x16 o0, o1;
#pragma unroll
  for (int i = 0; i < 16; ++i) { o0[i] = 0.f; o1[i] = 0.f; }
  float m = -1e30f, lsum = 0.f;

  const int nblk = qt + 1;
  for (int blk = w; blk < nblk; blk += 8) {
    const int kv0 = blk * 32;
    const f16* kr = kbase + (size_t)(kv0 + q31) * HS + 8 * hi;
    f16x8 ka0 = *(const f16x8*)(kr);
    f16x8 ka1 = *(const f16x8*)(kr + 16);
    f16x8 ka2 = *(const f16x8*)(kr + 32);
    f16x8 ka3 = *(const f16x8*)(kr + 48);

    f32x16 s;
#pragma unroll
    for (int i = 0; i < 16; ++i) s[i] = 0.f;
    s = __builtin_amdgcn_mfma_f32_32x32x16_f16(ka0, qb[0], s, 0, 0, 0);
    s = __builtin_amdgcn_mfma_f32_32x32x16_f16(ka1, qb[1], s, 0, 0, 0);
    s = __builtin_amdgcn_mfma_f32_32x32x16_f16(ka2, qb[2], s, 0, 0, 0);
    s = __builtin_amdgcn_mfma_f32_32x32x16_f16(ka3, qb[3], s, 0, 0, 0);

    const f16* vr = vbase + (size_t)q31 * T + kv0 + 8 * hi;
    f16x8 v00 = *(const f16x8*)(vr);
    f16x8 v01 = *(const f16x8*)(vr + 16);
    f16x8 v10 = *(const f16x8*)(vr + (size_t)32 * T);
    f16x8 v11 = *(const f16x8*)(vr + (size_t)32 * T + 16);

    if (blk == qt) {
#pragma unroll
      for (int r = 0; r < 16; ++r) {
        const int kl = (r & 3) + 8 * (r >> 2) + 4 * hi;
        if (kl > q31) s[r] = -1e30f;
      }
    }

    float pm = s[0];
#pragma unroll
    for (int r = 1; r < 16; ++r) pm = fmaxf(pm, s[r]);
    pm = fmaxf(pm, __shfl_xor(pm, 32));
    if (!__all(pm <= m + 32.f)) {
      const float mn = fmaxf(m, pm);
      const float r = EXP2((m - mn) * CEXP);
      lsum *= r;
#pragma unroll
      for (int i = 0; i < 16; ++i) { o0[i] *= r; o1[i] *= r; }
      m = mn;
    }

    float p[16];
    float ps = 0.f;
#pragma unroll
    for (int r = 0; r < 16; ++r) { p[r] = EXP2((s[r] - m) * CEXP); ps += p[r]; }
    ps += __shfl_xor(ps, 32);
    lsum += ps;

    u32 c[8], xg[8];
#pragma unroll
    for (int i = 0; i < 8; ++i) c[i] = pack2_f16(p[2 * i], p[2 * i + 1]);
#pragma unroll
    for (int i = 0; i < 8; ++i) xg[i] = (u32)__shfl_xor((int)c[i], 32);
    union { u32x4 u; f16x8 f; } f1, f2;
    f1.u = (u32x4){ hi ? xg[2] : c[0], hi ? xg[3] : c[1], hi ? c[2] : xg[0], hi ? c[3] : xg[1] };
    f2.u = (u32x4){ hi ? xg[6] : c[4], hi ? xg[7] : c[5], hi ? c[6] : xg[4], hi ? c[7] : xg[5] };

    o0 = __builtin_amdgcn_mfma_f32_32x32x16_f16(v00, f1.f, o0, 0, 0, 0);
    o0 = __builtin_amdgcn_mfma_f32_32x32x16_f16(v01, f2.f, o0, 0, 0, 0);
    o1 = __builtin_amdgcn_mfma_f32_32x32x16_f16(v10, f1.f, o1, 0, 0, 0);
    o1 = __builtin_amdgcn_mfma_f32_32x32x16_f16(v11, f2.f, o1, 0, 0, 0);
  }

  if (lane < 32) sMm[w][q31] = m;
  __syncthreads();
  float M = sMm[0][q31];
#pragma unroll
  for (int w2 = 1; w2 < 8; ++w2) M = fmaxf(M, sMm[w2][q31]);
  const float sc = EXP2((m - M) * CEXP);
  if (lane < 32) sLs[w][q31] = lsum * sc;
#pragma unroll
  for (int i = 0; i < 16; ++i) { o0[i] *= sc; o1[i] *= sc; }

  if (w >= 4) {
#pragma unroll
    for (int r = 0; r < 16; ++r) {
      const int d = (r & 3) + 8 * (r >> 2) + 4 * hi;
      sO[w - 4][d][q31] = o0[r];
      sO[w - 4][d + 32][q31] = o1[r];
    }
  }
  __syncthreads();
  if (w < 4) {
#pragma unroll
    for (int r = 0; r < 16; ++r) {
      const int d = (r & 3) + 8 * (r >> 2) + 4 * hi;
      sO[w][d][q31] += o0[r];
      sO[w][d + 32][q31] += o1[r];
    }
  }
  __syncthreads();

  const int q = tid >> 4;
  const int d0 = (tid & 15) * 4;
  float L = 0.f;
#pragma unroll
  for (int w2 = 0; w2 < 8; ++w2) L += sLs[w2][q];
  const float invL = 1.f / L;
  float4 rv;
  rv.x = (sO[0][d0 + 0][q] + sO[1][d0 + 0][q] + sO[2][d0 + 0][q] + sO[3][d0 + 0][q]) * invL;
  rv.y = (sO[0][d0 + 1][q] + sO[1][d0 + 1][q] + sO[2][d0 + 1][q] + sO[3][d0 + 1][q]) * invL;
  rv.z = (sO[0][d0 + 2][q] + sO[1][d0 + 2][q] + sO[2][d0 + 2][q] + sO[3][d0 + 2][q]) * invL;
  rv.w = (sO[0][d0 + 3][q] + sO[1][d0 + 3][q] + sO[2][d0 + 3][q] + sO[3][d0 + 3][q]) * invL;
  *(float4*)(out + (size_t)(b * T + q0 + q) * HS + d0) = rv;
}

// ---------------------------------------------------------------------------
extern "C" void kernel_launch(void* const* d_in, const int* in_sizes, int n_in,
                              void* d_out, int out_size, void* d_ws, size_t ws_size,
                              hipStream_t stream) {
  const float* q  = (const float*)d_in[0];
  const float* k  = (const float*)d_in[1];
  const float* v  = (const float*)d_in[2];
  const float* Wq = (const float*)d_in[3];
  const float* Wk = (const float*)d_in[4];
  const float* Wv = (const float*)d_in[5];
  float* out = (float*)d_out;

  f16* qh  = (f16*)d_ws;                       // [B*T][64]
  f16* kh  = qh  + (size_t)NBATCH * T * HS;    // [B*T][64]
  f16* vhT = kh  + (size_t)NBATCH * T * HS;    // [B][64][T]
  f16* WTf = vhT + (size_t)NBATCH * T * HS;    // [3][65536] fragment-packed

  wtrans_kernel<<<dim3(32, 3), 256, 0, stream>>>(Wq, Wk, Wv, WTf);
  proj_kernel<<<dim3(64, 3), 256, 0, stream>>>(q, k, v, WTf, qh, kh, vhT);
  attn_kernel<<<dim3(T / 32 * NBATCH), 512, 0, stream>>>(qh, kh, vhT, out);
}